// Round 7
// baseline (53.339 us; speedup 1.0000x reference)
//
#include <hip/hip_runtime.h>
#include <cstdint>
#include <cstddef>

#define BATCH 4
#define NTOK  4096
#define CCH   256
#define IMH   512
#define IMW   512

#define ROWS_PER_BLOCK 4
#define NBLOCKS (BATCH * NTOK / ROWS_PER_BLOCK)   // 4096

// diagnostic stream: 4096 blocks x 12 float4 x 256 threads x 16B = 201 MB
#define STREAM_F4_PER_THREAD 12
#define STREAM_BYTES ((size_t)NBLOCKS * STREAM_F4_PER_THREAD * 256 * 16)

typedef float v4f __attribute__((ext_vector_type(4)));

// ---------------------------------------------------------------------------
// Round-6 kernel + DIAGNOSTIC HBM stream (201 MB read of d_ws, value-sunk).
// Purpose: push this dispatch above the 40us harness fills so its profile row
// (dur, FETCH_SIZE, hbm_gbps) becomes visible in top-5, splitting "fixed
// harness floor" from "kernel time". Baseline work is unchanged and correct.
// ---------------------------------------------------------------------------
__global__ __launch_bounds__(256) void fused_diag_k(const float4* __restrict__ feat,
                                                    const float* __restrict__ im,
                                                    const int2* __restrict__ po,
                                                    const int4* __restrict__ ps4,
                                                    const v4f* __restrict__ stream_src,
                                                    float4* __restrict__ out_feat,
                                                    float* __restrict__ out_dis) {
    __shared__ int s_key[ROWS_PER_BLOCK];
    __shared__ int s_idx[ROWS_PER_BLOCK];

    const int tid = threadIdx.x;
    const int r0  = blockIdx.x * ROWS_PER_BLOCK;
    const int b   = r0 >> 12;

    if (tid < ROWS_PER_BLOCK) {
        int2 p = po[r0 + tid];
        s_key[tid] = (p.x << 16) | p.y;
        s_idx[tid] = 0x7FFFFFFF;
    }
    __syncthreads();

    // --- phase 1: permutation match via packed-key scan ---
    int kreg[ROWS_PER_BLOCK];
#pragma unroll
    for (int k = 0; k < ROWS_PER_BLOCK; ++k) kreg[k] = s_key[k];

    const int4* psb = ps4 + (size_t)b * (NTOK / 2);
#pragma unroll
    for (int it = 0; it < NTOK / 2 / 256; ++it) {
        const int u = it * 256 + tid;
        const int4 v = psb[u];
        const int e0 = (v.x << 16) | v.y;
        const int e1 = (v.z << 16) | v.w;
        const int j0 = 2 * u;
#pragma unroll
        for (int k = 0; k < ROWS_PER_BLOCK; ++k) {
            if (e0 == kreg[k]) atomicMin(&s_idx[k], j0);
            if (e1 == kreg[k]) atomicMin(&s_idx[k], j0 + 1);
        }
    }
    __syncthreads();

    // --- phase 2: gather + dis, one row per wave ---
    const int lane = tid & 63;
    const int w    = tid >> 6;

    const int row = r0 + w;
    const int idx = s_idx[w];
    const int key = s_key[w];

    const v4f fv = __builtin_nontemporal_load(
        (const v4f*)&feat[((size_t)(b * NTOK + idx)) * 64 + lane]);
    __builtin_nontemporal_store(fv, (v4f*)&out_feat[(size_t)row * 64 + lane]);

    float s = 0.f;
    if (lane < 48) {
        const int px  = key >> 16;
        const int py  = key & 0xFFFF;
        const int ch  = lane >> 4;
        const int k   = lane & 15;
        const int col = px * 4 + (k >> 2);
        const int r   = py * 4 + (k & 3);
        const float* base = im + (((size_t)(b * 3 + ch)) * IMH + r) * IMW + col;
        const float v = base[0];
        if (r > 0)         s += fabsf(v - base[-IMW]);
        if (r < IMH - 1)   s += fabsf(base[IMW] - v);
        if (col > 0)       s += fabsf(v - base[-1]);
        if (col < IMW - 1) s += fabsf(base[1] - v);
    }
    s += __shfl_xor(s, 1,  64);
    s += __shfl_xor(s, 2,  64);
    s += __shfl_xor(s, 4,  64);
    s += __shfl_xor(s, 8,  64);
    s += __shfl_xor(s, 16, 64);
    s += __shfl_xor(s, 32, 64);
    if (lane == 0) __builtin_nontemporal_store(s, &out_dis[row]);

    // --- DIAGNOSTIC: 201 MB coalesced HBM stream, value kept live via sink ---
    if (stream_src != nullptr) {
        const size_t chunk = (size_t)blockIdx.x * (STREAM_F4_PER_THREAD * 256);
        v4f acc = {0.f, 0.f, 0.f, 0.f};
#pragma unroll
        for (int r = 0; r < STREAM_F4_PER_THREAD; ++r) {
            acc += __builtin_nontemporal_load(&stream_src[chunk + r * 256 + tid]);
        }
        asm volatile("" :: "v"(acc.x), "v"(acc.y), "v"(acc.z), "v"(acc.w));
    }
}

extern "C" void kernel_launch(void* const* d_in, const int* in_sizes, int n_in,
                              void* d_out, int out_size, void* d_ws, size_t ws_size,
                              hipStream_t stream) {
    const float* feat         = (const float*)d_in[0];
    const float* images       = (const float*)d_in[1];
    const int*   pos_org      = (const int*)d_in[2];
    const int*   pos_shuffled = (const int*)d_in[3];

    float* out_feat = (float*)d_out;
    float* out_dis  = out_feat + (size_t)BATCH * NTOK * CCH;

    const v4f* stream_src = (ws_size >= STREAM_BYTES) ? (const v4f*)d_ws : nullptr;

    fused_diag_k<<<NBLOCKS, 256, 0, stream>>>(
        (const float4*)feat, images, (const int2*)pos_org,
        (const int4*)pos_shuffled, stream_src, (float4*)out_feat, out_dis);
}